// Round 6
// baseline (540.797 us; speedup 1.0000x reference)
//
#include <hip/hip_runtime.h>

namespace {

typedef unsigned short ushort_t;
typedef short s16x8 __attribute__((ext_vector_type(8)));
typedef float f32x4 __attribute__((ext_vector_type(4)));

constexpr int B_ = 2, C_ = 64, H_ = 192, W_ = 192;
constexpr int C4 = 256;
constexpr int NPIX = H_ * W_;                       // 36864
constexpr size_t NT = (size_t)B_ * C4 * NPIX;       // 18,874,368
constexpr int PB = NPIX / 32;                       // 1152 pixel-blocks per batch
constexpr float EPSV = 1e-20f;

constexpr int TILE = 32;
constexpr int TLH = TILE + 2;   // 34
constexpr int CHUNK = 2048;     // ushorts per tensor per k-chunk (4 KB)

__device__ __forceinline__ ushort_t f2bu(float x) {
    union { float f; unsigned u; } v; v.f = x;
    unsigned r = v.u + 0x7fffu + ((v.u >> 16) & 1u);   // RNE to bf16
    return (ushort_t)(r >> 16);
}
__device__ __forceinline__ float bu2f(ushort_t h) {
    union { unsigned u; float f; } v; v.u = ((unsigned)h) << 16;
    return v.f;
}

__device__ __forceinline__ void async_ld16(const ushort_t* g, ushort_t* l) {
    __builtin_amdgcn_global_load_lds(
        (const __attribute__((address_space(1))) unsigned int*)g,
        (__attribute__((address_space(3))) unsigned int*)l, 16, 0, 0);
}

// ---------------- cw -> split bf16 hi/lo + per-block cw partial sums ----------
__global__ __launch_bounds__(256) void k_prep(const float* __restrict__ cw,
                                              ushort_t* __restrict__ cwH,
                                              ushort_t* __restrict__ cwL,
                                              float* __restrict__ partial) {
    __shared__ float red[256];
    int tid = threadIdx.x;
    int i = blockIdx.x * 256 + tid;   // grid 256 -> 65536
    float w = cw[i];
    ushort_t h = f2bu(w);
    cwH[i] = h;
    cwL[i] = f2bu(w - bu2f(h));
    red[tid] = w; __syncthreads();
    for (int s2 = 128; s2 > 0; s2 >>= 1) { if (tid < s2) red[tid] += red[tid + s2]; __syncthreads(); }
    if (tid == 0) partial[blockIdx.x] = red[0];
}

// ---------------- tiny final reduction: sw sum + cw partials ----------------
__global__ __launch_bounds__(256) void k_sums2(const float* __restrict__ sw,
                                               const float* __restrict__ partial,
                                               float* __restrict__ sums) {
    __shared__ float red[256];
    int tid = threadIdx.x;
    float a = 0.f;
    for (int i = tid; i < C4 * 9; i += 256) a += sw[i];
    red[tid] = a; __syncthreads();
    for (int s2 = 128; s2 > 0; s2 >>= 1) { if (tid < s2) red[tid] += red[tid + s2]; __syncthreads(); }
    if (tid == 0) sums[0] = red[0];
    __syncthreads();
    red[tid] = partial[tid]; __syncthreads();
    for (int s2 = 128; s2 > 0; s2 >>= 1) { if (tid < s2) red[tid] += red[tid + s2]; __syncthreads(); }
    if (tid == 0) sums[1] = red[0];
}

// ---------------- fused stage 1 + stage 2 (depthwise conv) ----------------
// Divisions cancel: U = cs_prop*s_prop = (wp*cs*s + cfd*sfd)/(wp+1) and
// X = cs_spatial*s_spatial = conv(U)/sum_sw (up to den/(den+1e-20) == 1).
// k processed in two halves to halve LDS (19.2 KB -> 6 blocks/CU).
// Emits XP/YP packed split-bf16: element (b, pb, g, pix32, j) at
// ((b*PB+pb)*64 + g)*256 + pix*8 + j ; j = [hi k4 0..3 | lo k4 0..3].
__global__ __launch_bounds__(256, 6) void k_stage12(
    const float* __restrict__ d, const float* __restrict__ cd,
    const float* __restrict__ s, const float* __restrict__ cs,
    const float* __restrict__ w_s_from_d, const float* __restrict__ w_prop,
    const float* __restrict__ sw, const float* __restrict__ sums,
    ushort_t* __restrict__ XP, ushort_t* __restrict__ YP)
{
    __shared__ float u_[2][TLH][TLH + 1];   // 9,520 B
    __shared__ float v_[2][TLH][TLH + 1];   // 9,520 B
    __shared__ float swl[4][9];

    int tid = threadIdx.x;
    int blk = blockIdx.x;
    constexpr int TX = W_ / TILE, TY = H_ / TILE;   // 6 x 6
    int tx0 = blk % TX; blk /= TX;
    int ty0 = blk % TY; blk /= TY;
    int c = blk % C_;
    int b = blk / C_;
    int h0 = ty0 * TILE, w0 = tx0 * TILE;

    const float* dbc  = d  + (size_t)(b * C_ + c) * NPIX;
    const float* cdbc = cd + (size_t)(b * C_ + c) * NPIX;

    if (tid < 36) swl[tid / 9][tid % 9] = sw[(c * 4 + tid / 9) * 9 + tid % 9];

    float w0s = w_s_from_d[0];
    float wp  = w_prop[c];
    float inv_wp1 = 1.f / (wp + 1.f);
    float inv_sw  = 1.f / (sums[0] + EPSV);
    float b1 = wp * inv_wp1;

    uint2 keepX[4], keepY[4];   // half-0 packed results: .x = hi(k0)|hi(k1)<<16, .y = lo pair
    int pbw = w0 >> 5;

    #pragma unroll
    for (int hf = 0; hf < 2; ++hf) {
        if (hf) __syncthreads();   // half-0 conv readers done before LDS overwrite
        // stage 1 on the halo-1 grid (34x34); only direction 0 survives the
        // reference's argmax over identical stacked copies.
        for (int i = tid; i < TLH * TLH; i += 256) {
            int y = i / TLH, x = i - y * TLH;
            int gh = h0 - 1 + y, gw = w0 - 1 + x;
            if ((unsigned)gh < (unsigned)H_ && (unsigned)gw < (unsigned)W_) {
                float mn = 0.f, cmn = 0.f, mx = 0.f, cmx = 0.f;
                if (gh >= 1 && gw >= 1) {
                    size_t q = (size_t)(gh - 1) * W_ + (gw - 1);
                    mn = dbc[q]; cmn = cdbc[q];
                }
                if (gh < H_ - 1 && gw < W_ - 1) {
                    size_t q = (size_t)(gh + 1) * W_ + (gw + 1);
                    mx = dbc[q]; cmx = cdbc[q];
                }
                float r = __fdividef(mn, mx + EPSV);
                r = fminf(fmaxf(r, 0.f), 1.f);
                float sfd = r * fmaf(w0s, r, 1.f - w0s);
                float cfd = cmn * cmx;
                float a1 = cfd * sfd * inv_wp1;
                float c1 = cfd * inv_wp1;
                size_t gbase = (size_t)((b * C_ + c) * 4 + hf * 2) * NPIX + (size_t)gh * W_ + gw;
                #pragma unroll
                for (int k2 = 0; k2 < 2; ++k2) {
                    float s_v  = s[gbase + (size_t)k2 * NPIX];
                    float cs_v = cs[gbase + (size_t)k2 * NPIX];
                    float t = b1 * cs_v;
                    u_[k2][y][x] = fmaf(t, s_v, a1);   // cs_prop * s_prop
                    v_[k2][y][x] = t + c1;             // cs_prop
                }
            } else {
                #pragma unroll
                for (int k2 = 0; k2 < 2; ++k2) { u_[k2][y][x] = 0.f; v_[k2][y][x] = 0.f; }
            }
        }
        __syncthreads();

        // depthwise 3x3 for this half's 2 sub-channels
        #pragma unroll
        for (int p = 0; p < 4; ++p) {
            int i = p * 256 + tid;
            int ty = i >> 5, tx = i & 31;
            float xv[2], yv[2];
            #pragma unroll
            for (int k2 = 0; k2 < 2; ++k2) {
                int k = hf * 2 + k2;
                float nom = 0.f, den = 0.f;
                #pragma unroll
                for (int dy = 0; dy < 3; ++dy)
                    #pragma unroll
                    for (int dx = 0; dx < 3; ++dx) {
                        float wgt = swl[k][dy * 3 + dx];
                        nom = fmaf(wgt, u_[k2][ty + dy][tx + dx], nom);
                        den = fmaf(wgt, v_[k2][ty + dy][tx + dx], den);
                    }
                xv[k2] = nom * inv_sw;
                yv[k2] = den * inv_sw;
            }
            ushort_t xa = f2bu(xv[0]), xb = f2bu(xv[1]);
            ushort_t ya = f2bu(yv[0]), yb = f2bu(yv[1]);
            unsigned xh = (unsigned)xa | ((unsigned)xb << 16);
            unsigned xl = (unsigned)f2bu(xv[0] - bu2f(xa)) | ((unsigned)f2bu(xv[1] - bu2f(xb)) << 16);
            unsigned yh = (unsigned)ya | ((unsigned)yb << 16);
            unsigned yl = (unsigned)f2bu(yv[0] - bu2f(ya)) | ((unsigned)f2bu(yv[1] - bu2f(yb)) << 16);
            if (hf == 0) {
                keepX[p] = make_uint2(xh, xl);
                keepY[p] = make_uint2(yh, yl);
            } else {
                union { s16x8 v; unsigned u[4]; } X, Y;
                X.u[0] = keepX[p].x; X.u[1] = xh; X.u[2] = keepX[p].y; X.u[3] = xl;
                Y.u[0] = keepY[p].x; Y.u[1] = yh; Y.u[2] = keepY[p].y; Y.u[3] = yl;
                int pb = (h0 + ty) * (W_ / TILE) + pbw;
                size_t base = ((size_t)(b * PB + pb) * 64 + c) * 256 + (size_t)tx * 8;
                *(s16x8*)(XP + base) = X.v;
                *(s16x8*)(YP + base) = Y.v;
            }
        }
    }
}

// ---------------- stage 3: split-bf16 MFMA GEMM, monolithic LDS stage ----------------
// 512 threads (8 waves). Block tile: 256 o x 32 pix. Wave w: o in [w*32,(w+1)*32).
// Whole B-panel (X+Y = 64 KB) staged up-front via global_load_lds; TWO compute
// barriers. Epilogue transposes via LDS for full-line 16B/lane stores.
__global__ __launch_bounds__(512, 4) void k_stage3(
    const ushort_t* __restrict__ XP, const ushort_t* __restrict__ YP,
    const ushort_t* __restrict__ cwH, const ushort_t* __restrict__ cwL,
    const float* __restrict__ sums, float* __restrict__ out)
{
    __shared__ ushort_t stg[8 * 2 * CHUNK];   // 64 KiB: 8 chunks x [X 4KB | Y 4KB]

    int tid  = threadIdx.x;
    int wave = tid >> 6, lane = tid & 63;
    int l15 = lane & 15, l4 = lane >> 4;
    int pb = blockIdx.x;
    int b  = blockIdx.y;
    int o0 = wave * 32;

    size_t xbase = (size_t)(b * PB + pb) * 16384;   // ushorts: 64 g * 256
    const ushort_t* gsrc = ((wave & 4) ? YP : XP) + xbase
                         + (size_t)(wave & 3) * 512 + (size_t)lane * 8;
    ushort_t* lbase = stg + ((wave & 4) ? CHUNK : 0) + (wave & 3) * 512;

    f32x4 accn[2][2] = {};
    f32x4 accd[2][2] = {};
    s16x8 rx[2][2], ry[2][2];
    s16x8 rAh[2][2], rAl[2][2];

#define MFMA __builtin_amdgcn_mfma_f32_16x16x32_bf16

#define STAGE(KS) async_ld16(gsrc + (size_t)(KS) * 2048, lbase + (KS) * (2 * CHUNK))

#define LOADA(AB, KS) do {                                                        \
    _Pragma("unroll")                                                             \
    for (int m = 0; m < 2; ++m) {                                                 \
        size_t ro = (size_t)(o0 + m * 16 + l15) * C4 + (KS) * 32 + l4 * 8;        \
        rAh[AB][m] = *(const s16x8*)(cwH + ro);                                   \
        rAl[AB][m] = *(const s16x8*)(cwL + ro);                                   \
    } } while (0)

#define LOADB(KS) do {                                                            \
    const ushort_t* bp = stg + (KS) * (2 * CHUNK);                                \
    _Pragma("unroll")                                                             \
    for (int n = 0; n < 2; ++n)                                                   \
        _Pragma("unroll")                                                         \
        for (int gg = 0; gg < 2; ++gg) {                                          \
            int o_ = (l4 * 2 + gg) * 256 + (n * 16 + l15) * 8;                    \
            rx[n][gg] = *(const s16x8*)(bp + o_);                                 \
            ry[n][gg] = *(const s16x8*)(bp + CHUNK + o_);                         \
        } } while (0)

#define COMPUTE(AB) do {                                                          \
    _Pragma("unroll")                                                             \
    for (int n = 0; n < 2; ++n) {                                                 \
        s16x8 bxh = __builtin_shufflevector(rx[n][0], rx[n][1], 0,1,2,3, 8,9,10,11);   \
        s16x8 bxl = __builtin_shufflevector(rx[n][0], rx[n][1], 4,5,6,7, 12,13,14,15); \
        s16x8 byh = __builtin_shufflevector(ry[n][0], ry[n][1], 0,1,2,3, 8,9,10,11);   \
        s16x8 byl = __builtin_shufflevector(ry[n][0], ry[n][1], 4,5,6,7, 12,13,14,15); \
        _Pragma("unroll")                                                         \
        for (int m = 0; m < 2; ++m) {                                             \
            accn[m][n] = MFMA(rAh[AB][m], bxh, accn[m][n], 0, 0, 0);              \
            accn[m][n] = MFMA(rAh[AB][m], bxl, accn[m][n], 0, 0, 0);              \
            accn[m][n] = MFMA(rAl[AB][m], bxh, accn[m][n], 0, 0, 0);              \
            accd[m][n] = MFMA(rAh[AB][m], byh, accd[m][n], 0, 0, 0);              \
            accd[m][n] = MFMA(rAh[AB][m], byl, accd[m][n], 0, 0, 0);              \
            accd[m][n] = MFMA(rAl[AB][m], byh, accd[m][n], 0, 0, 0);              \
        } } } while (0)

    // prologue: stage ALL 8 chunks (8 VMEM), then A0 (4 VMEM)
    STAGE(0); STAGE(1); STAGE(2); STAGE(3);
    STAGE(4); STAGE(5); STAGE(6); STAGE(7);
    __builtin_amdgcn_sched_barrier(0);
    LOADA(0, 0);
    __builtin_amdgcn_sched_barrier(0);

    // wait: own S0..S3 retired (12 issued, <=8 outstanding -> >=4 retired)
    asm volatile("s_waitcnt vmcnt(8)" ::: "memory");
    __builtin_amdgcn_s_barrier();
    __builtin_amdgcn_sched_barrier(0);

    LOADA(1, 1); LOADB(0); COMPUTE(0);
    LOADA(0, 2); LOADB(1); COMPUTE(1);
    LOADA(1, 3); LOADB(2); COMPUTE(0);
    LOADA(0, 4); LOADB(3); COMPUTE(1);

    // wait: own S0..S7 retired (28 issued by now, <=20 outstanding -> >=8 retired)
    asm volatile("s_waitcnt vmcnt(20)" ::: "memory");
    __builtin_amdgcn_s_barrier();
    __builtin_amdgcn_sched_barrier(0);

    LOADA(1, 5); LOADB(4); COMPUTE(0);
    LOADA(0, 6); LOADB(5); COMPUTE(1);
    LOADA(1, 7); LOADB(6); COMPUTE(0);
    LOADB(7); COMPUTE(1);

#undef COMPUTE
#undef LOADB
#undef LOADA
#undef STAGE
#undef MFMA

    // -------- epilogue: LDS transpose -> full-line coalesced stores --------
    float* ts = reinterpret_cast<float*>(stg);   // 256 x 36 floats = 36,864 B
    float inv_scw = 1.f / (sums[1] + EPSV);
    __syncthreads();   // all LOADB consumers of stg finished

    #pragma unroll
    for (int pass2 = 0; pass2 < 2; ++pass2) {
        #pragma unroll
        for (int m = 0; m < 2; ++m)
            #pragma unroll
            for (int n = 0; n < 2; ++n)
                #pragma unroll
                for (int r = 0; r < 4; ++r) {
                    int o = o0 + m * 16 + l4 * 4 + r;
                    float nv = accn[m][n][r], dv = accd[m][n][r];
                    float val = pass2 ? dv * inv_scw : nv / (dv + EPSV);
                    ts[o * 36 + n * 16 + l15] = val;
                }
        __syncthreads();
        size_t gb = (pass2 ? NT : 0) + (size_t)b * C4 * NPIX + (size_t)pb * 32;
        int oo = tid >> 3, j = tid & 7;
        #pragma unroll
        for (int pass = 0; pass < 4; ++pass) {
            int o = pass * 64 + oo;
            f32x4 v = *(const f32x4*)&ts[o * 36 + j * 4];
            *(f32x4*)&out[gb + (size_t)o * NPIX + j * 4] = v;
        }
        if (pass2 == 0) __syncthreads();
    }
}

} // namespace

extern "C" void kernel_launch(void* const* d_in, const int* in_sizes, int n_in,
                              void* d_out, int out_size, void* d_ws, size_t ws_size,
                              hipStream_t stream) {
    const float* d    = (const float*)d_in[0];
    const float* cd   = (const float*)d_in[1];
    const float* s    = (const float*)d_in[2];
    const float* cs   = (const float*)d_in[3];
    const float* w_s  = (const float*)d_in[4];
    const float* wprp = (const float*)d_in[5];
    const float* cw   = (const float*)d_in[6];
    const float* sw   = (const float*)d_in[7];
    float* out = (float*)d_out;

    ushort_t* XP  = (ushort_t*)d_ws;
    ushort_t* YP  = XP + 2 * NT;
    ushort_t* cwH = YP + 2 * NT;
    ushort_t* cwL = cwH + C4 * C4;
    float* sums   = (float*)(cwL + C4 * C4);
    float* partial = sums + 2;

    k_prep<<<C4, 256, 0, stream>>>(cw, cwH, cwL, partial);
    k_sums2<<<1, 256, 0, stream>>>(sw, partial, sums);
    k_stage12<<<dim3(B_ * C_ * (H_ / TILE) * (W_ / TILE)), 256, 0, stream>>>(
        d, cd, s, cs, w_s, wprp, sw, sums, XP, YP);
    k_stage3<<<dim3(PB, B_), 512, 0, stream>>>(XP, YP, cwH, cwL, sums, out);
}

// Round 7
// 462.329 us; speedup vs baseline: 1.1697x; 1.1697x over previous
//
#include <hip/hip_runtime.h>

namespace {

typedef unsigned short ushort_t;
typedef short s16x8 __attribute__((ext_vector_type(8)));
typedef float f32x4 __attribute__((ext_vector_type(4)));

constexpr int B_ = 2, C_ = 64, H_ = 192, W_ = 192;
constexpr int C4 = 256;
constexpr int NPIX = H_ * W_;                       // 36864
constexpr size_t NT = (size_t)B_ * C4 * NPIX;       // 18,874,368
constexpr int PB = NPIX / 32;                       // 1152 pixel-blocks per batch
constexpr float EPSV = 1e-20f;

constexpr int TILE = 32;
constexpr int TLH = TILE + 2;   // 34
constexpr int CHUNK = 2048;     // ushorts per tensor per k-chunk (4 KB)

__device__ __forceinline__ ushort_t f2bu(float x) {
    union { float f; unsigned u; } v; v.f = x;
    unsigned r = v.u + 0x7fffu + ((v.u >> 16) & 1u);   // RNE to bf16
    return (ushort_t)(r >> 16);
}
__device__ __forceinline__ float bu2f(ushort_t h) {
    union { unsigned u; float f; } v; v.u = ((unsigned)h) << 16;
    return v.f;
}

__device__ __forceinline__ void async_ld16(const ushort_t* g, ushort_t* l) {
    __builtin_amdgcn_global_load_lds(
        (const __attribute__((address_space(1))) unsigned int*)g,
        (__attribute__((address_space(3))) unsigned int*)l, 16, 0, 0);
}

// ---------------- cw -> split bf16 hi/lo + per-block cw partial sums ----------
__global__ __launch_bounds__(256) void k_prep(const float* __restrict__ cw,
                                              ushort_t* __restrict__ cwH,
                                              ushort_t* __restrict__ cwL,
                                              float* __restrict__ partial) {
    __shared__ float red[256];
    int tid = threadIdx.x;
    int i = blockIdx.x * 256 + tid;   // grid 256 -> 65536
    float w = cw[i];
    ushort_t h = f2bu(w);
    cwH[i] = h;
    cwL[i] = f2bu(w - bu2f(h));
    red[tid] = w; __syncthreads();
    for (int s2 = 128; s2 > 0; s2 >>= 1) { if (tid < s2) red[tid] += red[tid + s2]; __syncthreads(); }
    if (tid == 0) partial[blockIdx.x] = red[0];
}

// ---------------- tiny final reduction: sw sum + cw partials ----------------
__global__ __launch_bounds__(256) void k_sums2(const float* __restrict__ sw,
                                               const float* __restrict__ partial,
                                               float* __restrict__ sums) {
    __shared__ float red[256];
    int tid = threadIdx.x;
    float a = 0.f;
    for (int i = tid; i < C4 * 9; i += 256) a += sw[i];
    red[tid] = a; __syncthreads();
    for (int s2 = 128; s2 > 0; s2 >>= 1) { if (tid < s2) red[tid] += red[tid + s2]; __syncthreads(); }
    if (tid == 0) sums[0] = red[0];
    __syncthreads();
    red[tid] = partial[tid]; __syncthreads();
    for (int s2 = 128; s2 > 0; s2 >>= 1) { if (tid < s2) red[tid] += red[tid + s2]; __syncthreads(); }
    if (tid == 0) sums[1] = red[0];
}

// ---------------- fused stage 1 + stage 2 (depthwise conv) ----------------
// Divisions cancel: U = cs_prop*s_prop = (wp*cs*s + cfd*sfd)/(wp+1) and
// X = cs_spatial*s_spatial = conv(U)/sum_sw (up to den/(den+1e-20) == 1).
// k-independent per-pixel fields a1 = cfd*sfd/(wp+1), c1 = cfd/(wp+1) are
// computed ONCE into LDS; per-k u/v tiles are staged sequentially so LDS
// stays at ~19.2 KB (no VGPR cap -> no spills; occupancy bound by VGPR only).
// Emits XP/YP packed split-bf16: element (b, pb, g, pix32, j) at
// ((b*PB+pb)*64 + g)*256 + pix*8 + j ; j = [hi of k=0..3 | lo of k=0..3].
__global__ __launch_bounds__(256) void k_stage12(
    const float* __restrict__ d, const float* __restrict__ cd,
    const float* __restrict__ s, const float* __restrict__ cs,
    const float* __restrict__ w_s_from_d, const float* __restrict__ w_prop,
    const float* __restrict__ sw, const float* __restrict__ sums,
    ushort_t* __restrict__ XP, ushort_t* __restrict__ YP)
{
    __shared__ float a1_[TLH][TLH + 1];   // 4,760 B each
    __shared__ float c1_[TLH][TLH + 1];
    __shared__ float u_[TLH][TLH + 1];
    __shared__ float v_[TLH][TLH + 1];
    __shared__ float swl[4][9];

    int tid = threadIdx.x;
    int blk = blockIdx.x;
    constexpr int TX = W_ / TILE, TY = H_ / TILE;   // 6 x 6
    int tx0 = blk % TX; blk /= TX;
    int ty0 = blk % TY; blk /= TY;
    int c = blk % C_;
    int b = blk / C_;
    int h0 = ty0 * TILE, w0 = tx0 * TILE;

    const float* dbc  = d  + (size_t)(b * C_ + c) * NPIX;
    const float* cdbc = cd + (size_t)(b * C_ + c) * NPIX;

    if (tid < 36) swl[tid / 9][tid % 9] = sw[(c * 4 + tid / 9) * 9 + tid % 9];

    float w0s = w_s_from_d[0];
    float wp  = w_prop[c];
    float inv_wp1 = 1.f / (wp + 1.f);
    float inv_sw  = 1.f / (sums[0] + EPSV);
    float b1 = wp * inv_wp1;

    // pass 0: k-independent stage-1 fields on the halo-1 grid (34x34).
    // Only direction 0 survives the reference's argmax over identical copies.
    for (int i = tid; i < TLH * TLH; i += 256) {
        int y = i / TLH, x = i - y * TLH;
        int gh = h0 - 1 + y, gw = w0 - 1 + x;
        float af = 0.f, cf = 0.f;
        if ((unsigned)gh < (unsigned)H_ && (unsigned)gw < (unsigned)W_) {
            float mn = 0.f, cmn = 0.f, mx = 0.f, cmx = 0.f;
            if (gh >= 1 && gw >= 1) {
                size_t q = (size_t)(gh - 1) * W_ + (gw - 1);
                mn = dbc[q]; cmn = cdbc[q];
            }
            if (gh < H_ - 1 && gw < W_ - 1) {
                size_t q = (size_t)(gh + 1) * W_ + (gw + 1);
                mx = dbc[q]; cmx = cdbc[q];
            }
            float r = __fdividef(mn, mx + EPSV);
            r = fminf(fmaxf(r, 0.f), 1.f);
            float sfd = r * fmaf(w0s, r, 1.f - w0s);
            float cfd = cmn * cmx;
            af = cfd * sfd * inv_wp1;
            cf = cfd * inv_wp1;
        }
        a1_[y][x] = af;
        c1_[y][x] = cf;
    }
    __syncthreads();

    s16x8 keepX[4], keepY[4];   // per p: [hi k0..3 | lo k0..3]
    int pbw = w0 >> 5;

    #pragma unroll
    for (int k = 0; k < 4; ++k) {
        if (k) __syncthreads();   // WAR: previous k's conv readers done
        // fill u/v for sub-channel k
        for (int i = tid; i < TLH * TLH; i += 256) {
            int y = i / TLH, x = i - y * TLH;
            int gh = h0 - 1 + y, gw = w0 - 1 + x;
            float uv = 0.f, vv = 0.f;
            if ((unsigned)gh < (unsigned)H_ && (unsigned)gw < (unsigned)W_) {
                size_t gidx = (size_t)((b * C_ + c) * 4 + k) * NPIX + (size_t)gh * W_ + gw;
                float s_v  = s[gidx];
                float cs_v = cs[gidx];
                float t = b1 * cs_v;
                uv = fmaf(t, s_v, a1_[y][x]);   // cs_prop * s_prop
                vv = t + c1_[y][x];             // cs_prop
            }
            u_[y][x] = uv;
            v_[y][x] = vv;
        }
        __syncthreads();
        // depthwise 3x3 for sub-channel k; pack into keep registers
        #pragma unroll
        for (int p = 0; p < 4; ++p) {
            int i = p * 256 + tid;
            int ty = i >> 5, tx = i & 31;
            float nom = 0.f, den = 0.f;
            #pragma unroll
            for (int dy = 0; dy < 3; ++dy)
                #pragma unroll
                for (int dx = 0; dx < 3; ++dx) {
                    float wgt = swl[k][dy * 3 + dx];
                    nom = fmaf(wgt, u_[ty + dy][tx + dx], nom);
                    den = fmaf(wgt, v_[ty + dy][tx + dx], den);
                }
            float xv = nom * inv_sw;
            float yv = den * inv_sw;
            ushort_t hx = f2bu(xv);
            ushort_t hy = f2bu(yv);
            keepX[p][k]     = (short)hx;
            keepX[p][4 + k] = (short)f2bu(xv - bu2f(hx));
            keepY[p][k]     = (short)hy;
            keepY[p][4 + k] = (short)f2bu(yv - bu2f(hy));
        }
    }

    // fully-coalesced 16B stores (exact-traffic pattern: 147.5 MB total)
    #pragma unroll
    for (int p = 0; p < 4; ++p) {
        int i = p * 256 + tid;
        int ty = i >> 5, tx = i & 31;
        int pb = (h0 + ty) * (W_ / TILE) + pbw;
        size_t base = ((size_t)(b * PB + pb) * 64 + c) * 256 + (size_t)tx * 8;
        *(s16x8*)(XP + base) = keepX[p];
        *(s16x8*)(YP + base) = keepY[p];
    }
}

// ---------------- stage 3: split-bf16 MFMA GEMM, monolithic LDS stage ----------------
// 512 threads (8 waves). Block tile: 256 o x 32 pix. Wave w: o in [w*32,(w+1)*32).
// Whole B-panel (X+Y = 64 KB) staged up-front via global_load_lds; TWO compute
// barriers. Epilogue transposes via LDS for full-line 16B/lane stores.
__global__ __launch_bounds__(512, 4) void k_stage3(
    const ushort_t* __restrict__ XP, const ushort_t* __restrict__ YP,
    const ushort_t* __restrict__ cwH, const ushort_t* __restrict__ cwL,
    const float* __restrict__ sums, float* __restrict__ out)
{
    __shared__ ushort_t stg[8 * 2 * CHUNK];   // 64 KiB: 8 chunks x [X 4KB | Y 4KB]

    int tid  = threadIdx.x;
    int wave = tid >> 6, lane = tid & 63;
    int l15 = lane & 15, l4 = lane >> 4;
    int pb = blockIdx.x;
    int b  = blockIdx.y;
    int o0 = wave * 32;

    size_t xbase = (size_t)(b * PB + pb) * 16384;   // ushorts: 64 g * 256
    const ushort_t* gsrc = ((wave & 4) ? YP : XP) + xbase
                         + (size_t)(wave & 3) * 512 + (size_t)lane * 8;
    ushort_t* lbase = stg + ((wave & 4) ? CHUNK : 0) + (wave & 3) * 512;

    f32x4 accn[2][2] = {};
    f32x4 accd[2][2] = {};
    s16x8 rx[2][2], ry[2][2];
    s16x8 rAh[2][2], rAl[2][2];

#define MFMA __builtin_amdgcn_mfma_f32_16x16x32_bf16

#define STAGE(KS) async_ld16(gsrc + (size_t)(KS) * 2048, lbase + (KS) * (2 * CHUNK))

#define LOADA(AB, KS) do {                                                        \
    _Pragma("unroll")                                                             \
    for (int m = 0; m < 2; ++m) {                                                 \
        size_t ro = (size_t)(o0 + m * 16 + l15) * C4 + (KS) * 32 + l4 * 8;        \
        rAh[AB][m] = *(const s16x8*)(cwH + ro);                                   \
        rAl[AB][m] = *(const s16x8*)(cwL + ro);                                   \
    } } while (0)

#define LOADB(KS) do {                                                            \
    const ushort_t* bp = stg + (KS) * (2 * CHUNK);                                \
    _Pragma("unroll")                                                             \
    for (int n = 0; n < 2; ++n)                                                   \
        _Pragma("unroll")                                                         \
        for (int gg = 0; gg < 2; ++gg) {                                          \
            int o_ = (l4 * 2 + gg) * 256 + (n * 16 + l15) * 8;                    \
            rx[n][gg] = *(const s16x8*)(bp + o_);                                 \
            ry[n][gg] = *(const s16x8*)(bp + CHUNK + o_);                         \
        } } while (0)

#define COMPUTE(AB) do {                                                          \
    _Pragma("unroll")                                                             \
    for (int n = 0; n < 2; ++n) {                                                 \
        s16x8 bxh = __builtin_shufflevector(rx[n][0], rx[n][1], 0,1,2,3, 8,9,10,11);   \
        s16x8 bxl = __builtin_shufflevector(rx[n][0], rx[n][1], 4,5,6,7, 12,13,14,15); \
        s16x8 byh = __builtin_shufflevector(ry[n][0], ry[n][1], 0,1,2,3, 8,9,10,11);   \
        s16x8 byl = __builtin_shufflevector(ry[n][0], ry[n][1], 4,5,6,7, 12,13,14,15); \
        _Pragma("unroll")                                                         \
        for (int m = 0; m < 2; ++m) {                                             \
            accn[m][n] = MFMA(rAh[AB][m], bxh, accn[m][n], 0, 0, 0);              \
            accn[m][n] = MFMA(rAh[AB][m], bxl, accn[m][n], 0, 0, 0);              \
            accn[m][n] = MFMA(rAl[AB][m], bxh, accn[m][n], 0, 0, 0);              \
            accd[m][n] = MFMA(rAh[AB][m], byh, accd[m][n], 0, 0, 0);              \
            accd[m][n] = MFMA(rAh[AB][m], byl, accd[m][n], 0, 0, 0);              \
            accd[m][n] = MFMA(rAl[AB][m], byh, accd[m][n], 0, 0, 0);              \
        } } } while (0)

    // prologue: stage ALL 8 chunks (8 VMEM), then A0 (4 VMEM)
    STAGE(0); STAGE(1); STAGE(2); STAGE(3);
    STAGE(4); STAGE(5); STAGE(6); STAGE(7);
    __builtin_amdgcn_sched_barrier(0);
    LOADA(0, 0);
    __builtin_amdgcn_sched_barrier(0);

    // wait: own S0..S3 retired (12 issued, <=8 outstanding -> >=4 retired)
    asm volatile("s_waitcnt vmcnt(8)" ::: "memory");
    __builtin_amdgcn_s_barrier();
    __builtin_amdgcn_sched_barrier(0);

    LOADA(1, 1); LOADB(0); COMPUTE(0);
    LOADA(0, 2); LOADB(1); COMPUTE(1);
    LOADA(1, 3); LOADB(2); COMPUTE(0);
    LOADA(0, 4); LOADB(3); COMPUTE(1);

    // wait: own S0..S7 retired (28 issued by now, <=20 outstanding -> >=8 retired)
    asm volatile("s_waitcnt vmcnt(20)" ::: "memory");
    __builtin_amdgcn_s_barrier();
    __builtin_amdgcn_sched_barrier(0);

    LOADA(1, 5); LOADB(4); COMPUTE(0);
    LOADA(0, 6); LOADB(5); COMPUTE(1);
    LOADA(1, 7); LOADB(6); COMPUTE(0);
    LOADB(7); COMPUTE(1);

#undef COMPUTE
#undef LOADB
#undef LOADA
#undef STAGE
#undef MFMA

    // -------- epilogue: LDS transpose -> full-line coalesced stores --------
    float* ts = reinterpret_cast<float*>(stg);   // 256 x 36 floats = 36,864 B
    float inv_scw = 1.f / (sums[1] + EPSV);
    __syncthreads();   // all LOADB consumers of stg finished

    #pragma unroll
    for (int pass2 = 0; pass2 < 2; ++pass2) {
        #pragma unroll
        for (int m = 0; m < 2; ++m)
            #pragma unroll
            for (int n = 0; n < 2; ++n)
                #pragma unroll
                for (int r = 0; r < 4; ++r) {
                    int o = o0 + m * 16 + l4 * 4 + r;
                    float nv = accn[m][n][r], dv = accd[m][n][r];
                    float val = pass2 ? dv * inv_scw : nv / (dv + EPSV);
                    ts[o * 36 + n * 16 + l15] = val;
                }
        __syncthreads();
        size_t gb = (pass2 ? NT : 0) + (size_t)b * C4 * NPIX + (size_t)pb * 32;
        int oo = tid >> 3, j = tid & 7;
        #pragma unroll
        for (int pass = 0; pass < 4; ++pass) {
            int o = pass * 64 + oo;
            f32x4 v = *(const f32x4*)&ts[o * 36 + j * 4];
            *(f32x4*)&out[gb + (size_t)o * NPIX + j * 4] = v;
        }
        if (pass2 == 0) __syncthreads();
    }
}

} // namespace

extern "C" void kernel_launch(void* const* d_in, const int* in_sizes, int n_in,
                              void* d_out, int out_size, void* d_ws, size_t ws_size,
                              hipStream_t stream) {
    const float* d    = (const float*)d_in[0];
    const float* cd   = (const float*)d_in[1];
    const float* s    = (const float*)d_in[2];
    const float* cs   = (const float*)d_in[3];
    const float* w_s  = (const float*)d_in[4];
    const float* wprp = (const float*)d_in[5];
    const float* cw   = (const float*)d_in[6];
    const float* sw   = (const float*)d_in[7];
    float* out = (float*)d_out;

    ushort_t* XP  = (ushort_t*)d_ws;
    ushort_t* YP  = XP + 2 * NT;
    ushort_t* cwH = YP + 2 * NT;
    ushort_t* cwL = cwH + C4 * C4;
    float* sums   = (float*)(cwL + C4 * C4);
    float* partial = sums + 2;

    k_prep<<<C4, 256, 0, stream>>>(cw, cwH, cwL, partial);
    k_sums2<<<1, 256, 0, stream>>>(sw, partial, sums);
    k_stage12<<<dim3(B_ * C_ * (H_ / TILE) * (W_ / TILE)), 256, 0, stream>>>(
        d, cd, s, cs, w_s, wprp, sw, sums, XP, YP);
    k_stage3<<<dim3(PB, B_), 512, 0, stream>>>(XP, YP, cwH, cwL, sums, out);
}

// Round 8
// 297.279 us; speedup vs baseline: 1.8192x; 1.5552x over previous
//
#include <hip/hip_runtime.h>

namespace {

typedef unsigned short ushort_t;
typedef short s16x8 __attribute__((ext_vector_type(8)));
typedef float f32x4 __attribute__((ext_vector_type(4)));

constexpr int B_ = 2, C_ = 64, H_ = 192, W_ = 192;
constexpr int C4 = 256;
constexpr int NPIX = H_ * W_;                       // 36864
constexpr size_t NT = (size_t)B_ * C4 * NPIX;       // 18,874,368
constexpr int PB = NPIX / 32;                       // 1152 pixel-blocks per batch
constexpr float EPSV = 1e-20f;

constexpr int TILE = 32;
constexpr int TLH = TILE + 2;   // 34
constexpr int CHUNK = 2048;     // ushorts per tensor per k-chunk (4 KB)

__device__ __forceinline__ ushort_t f2bu(float x) {
    union { float f; unsigned u; } v; v.f = x;
    unsigned r = v.u + 0x7fffu + ((v.u >> 16) & 1u);   // RNE to bf16
    return (ushort_t)(r >> 16);
}
__device__ __forceinline__ float bu2f(ushort_t h) {
    union { unsigned u; float f; } v; v.u = ((unsigned)h) << 16;
    return v.f;
}

__device__ __forceinline__ void async_ld16(const ushort_t* g, ushort_t* l) {
    __builtin_amdgcn_global_load_lds(
        (const __attribute__((address_space(1))) unsigned int*)g,
        (__attribute__((address_space(3))) unsigned int*)l, 16, 0, 0);
}

// ---------------- cw -> split bf16 hi/lo + per-block cw partial sums ----------
__global__ __launch_bounds__(256) void k_prep(const float* __restrict__ cw,
                                              ushort_t* __restrict__ cwH,
                                              ushort_t* __restrict__ cwL,
                                              float* __restrict__ partial) {
    __shared__ float red[256];
    int tid = threadIdx.x;
    int i = blockIdx.x * 256 + tid;   // grid 256 -> 65536
    float w = cw[i];
    ushort_t h = f2bu(w);
    cwH[i] = h;
    cwL[i] = f2bu(w - bu2f(h));
    red[tid] = w; __syncthreads();
    for (int s2 = 128; s2 > 0; s2 >>= 1) { if (tid < s2) red[tid] += red[tid + s2]; __syncthreads(); }
    if (tid == 0) partial[blockIdx.x] = red[0];
}

// ---------------- tiny final reduction: sw sum + cw partials ----------------
__global__ __launch_bounds__(256) void k_sums2(const float* __restrict__ sw,
                                               const float* __restrict__ partial,
                                               float* __restrict__ sums) {
    __shared__ float red[256];
    int tid = threadIdx.x;
    float a = 0.f;
    for (int i = tid; i < C4 * 9; i += 256) a += sw[i];
    red[tid] = a; __syncthreads();
    for (int s2 = 128; s2 > 0; s2 >>= 1) { if (tid < s2) red[tid] += red[tid + s2]; __syncthreads(); }
    if (tid == 0) sums[0] = red[0];
    __syncthreads();
    red[tid] = partial[tid]; __syncthreads();
    for (int s2 = 128; s2 > 0; s2 >>= 1) { if (tid < s2) red[tid] += red[tid + s2]; __syncthreads(); }
    if (tid == 0) sums[1] = red[0];
}

// ---------------- fused stage 1 + stage 2 (depthwise conv) ----------------
// Divisions cancel: U = cs_prop*s_prop = (wp*cs*s + cfd*sfd)/(wp+1) and
// X = cs_spatial*s_spatial = conv(U)/sum_sw (up to den/(den+1e-20) == 1).
// k processed in two halves -> 19.2 KB LDS -> 8 blocks/CU by LDS. NO VGPR cap
// (R6's (256,6) cap caused 6x spill traffic); compiler takes what it needs.
// Emits XP/YP packed split-bf16: element (b, pb, g, pix32, j) at
// ((b*PB+pb)*64 + g)*256 + pix*8 + j ; j = [hi of k=0..3 | lo of k=0..3].
__global__ __launch_bounds__(256) void k_stage12(
    const float* __restrict__ d, const float* __restrict__ cd,
    const float* __restrict__ s, const float* __restrict__ cs,
    const float* __restrict__ w_s_from_d, const float* __restrict__ w_prop,
    const float* __restrict__ sw, const float* __restrict__ sums,
    ushort_t* __restrict__ XP, ushort_t* __restrict__ YP)
{
    __shared__ float u_[2][TLH][TLH + 1];   // 9,520 B
    __shared__ float v_[2][TLH][TLH + 1];   // 9,520 B
    __shared__ float swl[4][9];

    int tid = threadIdx.x;
    int blk = blockIdx.x;
    constexpr int TX = W_ / TILE, TY = H_ / TILE;   // 6 x 6
    int tx0 = blk % TX; blk /= TX;
    int ty0 = blk % TY; blk /= TY;
    int c = blk % C_;
    int b = blk / C_;
    int h0 = ty0 * TILE, w0 = tx0 * TILE;

    const float* dbc  = d  + (size_t)(b * C_ + c) * NPIX;
    const float* cdbc = cd + (size_t)(b * C_ + c) * NPIX;

    if (tid < 36) swl[tid / 9][tid % 9] = sw[(c * 4 + tid / 9) * 9 + tid % 9];

    float w0s = w_s_from_d[0];
    float wp  = w_prop[c];
    float inv_wp1 = 1.f / (wp + 1.f);
    float inv_sw  = 1.f / (sums[0] + EPSV);
    float b1 = wp * inv_wp1;

    uint2 keepX[4], keepY[4];   // half-0 packed results: .x = hi(k0)|hi(k1)<<16, .y = lo pair
    int pbw = w0 >> 5;

    #pragma unroll
    for (int hf = 0; hf < 2; ++hf) {
        if (hf) __syncthreads();   // half-0 conv readers done before LDS overwrite
        // stage 1 on the halo-1 grid (34x34); only direction 0 survives the
        // reference's argmax over identical stacked copies.
        for (int i = tid; i < TLH * TLH; i += 256) {
            int y = i / TLH, x = i - y * TLH;
            int gh = h0 - 1 + y, gw = w0 - 1 + x;
            if ((unsigned)gh < (unsigned)H_ && (unsigned)gw < (unsigned)W_) {
                float mn = 0.f, cmn = 0.f, mx = 0.f, cmx = 0.f;
                if (gh >= 1 && gw >= 1) {
                    size_t q = (size_t)(gh - 1) * W_ + (gw - 1);
                    mn = dbc[q]; cmn = cdbc[q];
                }
                if (gh < H_ - 1 && gw < W_ - 1) {
                    size_t q = (size_t)(gh + 1) * W_ + (gw + 1);
                    mx = dbc[q]; cmx = cdbc[q];
                }
                float r = __fdividef(mn, mx + EPSV);
                r = fminf(fmaxf(r, 0.f), 1.f);
                float sfd = r * fmaf(w0s, r, 1.f - w0s);
                float cfd = cmn * cmx;
                float a1 = cfd * sfd * inv_wp1;
                float c1 = cfd * inv_wp1;
                size_t gbase = (size_t)((b * C_ + c) * 4 + hf * 2) * NPIX + (size_t)gh * W_ + gw;
                #pragma unroll
                for (int k2 = 0; k2 < 2; ++k2) {
                    float s_v  = s[gbase + (size_t)k2 * NPIX];
                    float cs_v = cs[gbase + (size_t)k2 * NPIX];
                    float t = b1 * cs_v;
                    u_[k2][y][x] = fmaf(t, s_v, a1);   // cs_prop * s_prop
                    v_[k2][y][x] = t + c1;             // cs_prop
                }
            } else {
                #pragma unroll
                for (int k2 = 0; k2 < 2; ++k2) { u_[k2][y][x] = 0.f; v_[k2][y][x] = 0.f; }
            }
        }
        __syncthreads();

        // depthwise 3x3 for this half's 2 sub-channels
        #pragma unroll
        for (int p = 0; p < 4; ++p) {
            int i = p * 256 + tid;
            int ty = i >> 5, tx = i & 31;
            float xv[2], yv[2];
            #pragma unroll
            for (int k2 = 0; k2 < 2; ++k2) {
                int k = hf * 2 + k2;
                float nom = 0.f, den = 0.f;
                #pragma unroll
                for (int dy = 0; dy < 3; ++dy)
                    #pragma unroll
                    for (int dx = 0; dx < 3; ++dx) {
                        float wgt = swl[k][dy * 3 + dx];
                        nom = fmaf(wgt, u_[k2][ty + dy][tx + dx], nom);
                        den = fmaf(wgt, v_[k2][ty + dy][tx + dx], den);
                    }
                xv[k2] = nom * inv_sw;
                yv[k2] = den * inv_sw;
            }
            ushort_t xa = f2bu(xv[0]), xb = f2bu(xv[1]);
            ushort_t ya = f2bu(yv[0]), yb = f2bu(yv[1]);
            unsigned xh = (unsigned)xa | ((unsigned)xb << 16);
            unsigned xl = (unsigned)f2bu(xv[0] - bu2f(xa)) | ((unsigned)f2bu(xv[1] - bu2f(xb)) << 16);
            unsigned yh = (unsigned)ya | ((unsigned)yb << 16);
            unsigned yl = (unsigned)f2bu(yv[0] - bu2f(ya)) | ((unsigned)f2bu(yv[1] - bu2f(yb)) << 16);
            if (hf == 0) {
                keepX[p] = make_uint2(xh, xl);
                keepY[p] = make_uint2(yh, yl);
            } else {
                union { s16x8 v; unsigned u[4]; } X, Y;
                X.u[0] = keepX[p].x; X.u[1] = xh; X.u[2] = keepX[p].y; X.u[3] = xl;
                Y.u[0] = keepY[p].x; Y.u[1] = yh; Y.u[2] = keepY[p].y; Y.u[3] = yl;
                int pb = (h0 + ty) * (W_ / TILE) + pbw;
                size_t base = ((size_t)(b * PB + pb) * 64 + c) * 256 + (size_t)tx * 8;
                *(s16x8*)(XP + base) = X.v;
                *(s16x8*)(YP + base) = Y.v;
            }
        }
    }
}

// ---------------- stage 3: split-bf16 MFMA GEMM, monolithic LDS stage ----------------
// 512 threads (8 waves). Block tile: 256 o x 32 pix. Wave w: o in [w*32,(w+1)*32).
// Whole B-panel (X+Y = 64 KB) staged up-front via global_load_lds; TWO compute
// barriers. Epilogue transposes via LDS for full-line 16B/lane stores.
__global__ __launch_bounds__(512, 4) void k_stage3(
    const ushort_t* __restrict__ XP, const ushort_t* __restrict__ YP,
    const ushort_t* __restrict__ cwH, const ushort_t* __restrict__ cwL,
    const float* __restrict__ sums, float* __restrict__ out)
{
    __shared__ ushort_t stg[8 * 2 * CHUNK];   // 64 KiB: 8 chunks x [X 4KB | Y 4KB]

    int tid  = threadIdx.x;
    int wave = tid >> 6, lane = tid & 63;
    int l15 = lane & 15, l4 = lane >> 4;
    int pb = blockIdx.x;
    int b  = blockIdx.y;
    int o0 = wave * 32;

    size_t xbase = (size_t)(b * PB + pb) * 16384;   // ushorts: 64 g * 256
    const ushort_t* gsrc = ((wave & 4) ? YP : XP) + xbase
                         + (size_t)(wave & 3) * 512 + (size_t)lane * 8;
    ushort_t* lbase = stg + ((wave & 4) ? CHUNK : 0) + (wave & 3) * 512;

    f32x4 accn[2][2] = {};
    f32x4 accd[2][2] = {};
    s16x8 rx[2][2], ry[2][2];
    s16x8 rAh[2][2], rAl[2][2];

#define MFMA __builtin_amdgcn_mfma_f32_16x16x32_bf16

#define STAGE(KS) async_ld16(gsrc + (size_t)(KS) * 2048, lbase + (KS) * (2 * CHUNK))

#define LOADA(AB, KS) do {                                                        \
    _Pragma("unroll")                                                             \
    for (int m = 0; m < 2; ++m) {                                                 \
        size_t ro = (size_t)(o0 + m * 16 + l15) * C4 + (KS) * 32 + l4 * 8;        \
        rAh[AB][m] = *(const s16x8*)(cwH + ro);                                   \
        rAl[AB][m] = *(const s16x8*)(cwL + ro);                                   \
    } } while (0)

#define LOADB(KS) do {                                                            \
    const ushort_t* bp = stg + (KS) * (2 * CHUNK);                                \
    _Pragma("unroll")                                                             \
    for (int n = 0; n < 2; ++n)                                                   \
        _Pragma("unroll")                                                         \
        for (int gg = 0; gg < 2; ++gg) {                                          \
            int o_ = (l4 * 2 + gg) * 256 + (n * 16 + l15) * 8;                    \
            rx[n][gg] = *(const s16x8*)(bp + o_);                                 \
            ry[n][gg] = *(const s16x8*)(bp + CHUNK + o_);                         \
        } } while (0)

#define COMPUTE(AB) do {                                                          \
    _Pragma("unroll")                                                             \
    for (int n = 0; n < 2; ++n) {                                                 \
        s16x8 bxh = __builtin_shufflevector(rx[n][0], rx[n][1], 0,1,2,3, 8,9,10,11);   \
        s16x8 bxl = __builtin_shufflevector(rx[n][0], rx[n][1], 4,5,6,7, 12,13,14,15); \
        s16x8 byh = __builtin_shufflevector(ry[n][0], ry[n][1], 0,1,2,3, 8,9,10,11);   \
        s16x8 byl = __builtin_shufflevector(ry[n][0], ry[n][1], 4,5,6,7, 12,13,14,15); \
        _Pragma("unroll")                                                         \
        for (int m = 0; m < 2; ++m) {                                             \
            accn[m][n] = MFMA(rAh[AB][m], bxh, accn[m][n], 0, 0, 0);              \
            accn[m][n] = MFMA(rAh[AB][m], bxl, accn[m][n], 0, 0, 0);              \
            accn[m][n] = MFMA(rAl[AB][m], bxh, accn[m][n], 0, 0, 0);              \
            accd[m][n] = MFMA(rAh[AB][m], byh, accd[m][n], 0, 0, 0);              \
            accd[m][n] = MFMA(rAh[AB][m], byl, accd[m][n], 0, 0, 0);              \
            accd[m][n] = MFMA(rAl[AB][m], byh, accd[m][n], 0, 0, 0);              \
        } } } while (0)

    // prologue: stage ALL 8 chunks (8 VMEM), then A0 (4 VMEM)
    STAGE(0); STAGE(1); STAGE(2); STAGE(3);
    STAGE(4); STAGE(5); STAGE(6); STAGE(7);
    __builtin_amdgcn_sched_barrier(0);
    LOADA(0, 0);
    __builtin_amdgcn_sched_barrier(0);

    // wait: own S0..S3 retired (12 issued, <=8 outstanding -> >=4 retired)
    asm volatile("s_waitcnt vmcnt(8)" ::: "memory");
    __builtin_amdgcn_s_barrier();
    __builtin_amdgcn_sched_barrier(0);

    LOADA(1, 1); LOADB(0); COMPUTE(0);
    LOADA(0, 2); LOADB(1); COMPUTE(1);
    LOADA(1, 3); LOADB(2); COMPUTE(0);
    LOADA(0, 4); LOADB(3); COMPUTE(1);

    // wait: own S0..S7 retired (28 issued by now, <=20 outstanding -> >=8 retired)
    asm volatile("s_waitcnt vmcnt(20)" ::: "memory");
    __builtin_amdgcn_s_barrier();
    __builtin_amdgcn_sched_barrier(0);

    LOADA(1, 5); LOADB(4); COMPUTE(0);
    LOADA(0, 6); LOADB(5); COMPUTE(1);
    LOADA(1, 7); LOADB(6); COMPUTE(0);
    LOADB(7); COMPUTE(1);

#undef COMPUTE
#undef LOADB
#undef LOADA
#undef STAGE
#undef MFMA

    // -------- epilogue: LDS transpose -> full-line coalesced stores --------
    float* ts = reinterpret_cast<float*>(stg);   // 256 x 36 floats = 36,864 B
    float inv_scw = 1.f / (sums[1] + EPSV);
    __syncthreads();   // all LOADB consumers of stg finished

    #pragma unroll
    for (int pass2 = 0; pass2 < 2; ++pass2) {
        #pragma unroll
        for (int m = 0; m < 2; ++m)
            #pragma unroll
            for (int n = 0; n < 2; ++n)
                #pragma unroll
                for (int r = 0; r < 4; ++r) {
                    int o = o0 + m * 16 + l4 * 4 + r;
                    float nv = accn[m][n][r], dv = accd[m][n][r];
                    float val = pass2 ? dv * inv_scw : nv / (dv + EPSV);
                    ts[o * 36 + n * 16 + l15] = val;
                }
        __syncthreads();
        size_t gb = (pass2 ? NT : 0) + (size_t)b * C4 * NPIX + (size_t)pb * 32;
        int oo = tid >> 3, j = tid & 7;
        #pragma unroll
        for (int pass = 0; pass < 4; ++pass) {
            int o = pass * 64 + oo;
            f32x4 v = *(const f32x4*)&ts[o * 36 + j * 4];
            *(f32x4*)&out[gb + (size_t)o * NPIX + j * 4] = v;
        }
        if (pass2 == 0) __syncthreads();
    }
}

} // namespace

extern "C" void kernel_launch(void* const* d_in, const int* in_sizes, int n_in,
                              void* d_out, int out_size, void* d_ws, size_t ws_size,
                              hipStream_t stream) {
    const float* d    = (const float*)d_in[0];
    const float* cd   = (const float*)d_in[1];
    const float* s    = (const float*)d_in[2];
    const float* cs   = (const float*)d_in[3];
    const float* w_s  = (const float*)d_in[4];
    const float* wprp = (const float*)d_in[5];
    const float* cw   = (const float*)d_in[6];
    const float* sw   = (const float*)d_in[7];
    float* out = (float*)d_out;

    ushort_t* XP  = (ushort_t*)d_ws;
    ushort_t* YP  = XP + 2 * NT;
    ushort_t* cwH = YP + 2 * NT;
    ushort_t* cwL = cwH + C4 * C4;
    float* sums   = (float*)(cwL + C4 * C4);
    float* partial = sums + 2;

    k_prep<<<C4, 256, 0, stream>>>(cw, cwH, cwL, partial);
    k_sums2<<<1, 256, 0, stream>>>(sw, partial, sums);
    k_stage12<<<dim3(B_ * C_ * (H_ / TILE) * (W_ / TILE)), 256, 0, stream>>>(
        d, cd, s, cs, w_s, wprp, sw, sums, XP, YP);
    k_stage3<<<dim3(PB, B_), 512, 0, stream>>>(XP, YP, cwH, cwL, sums, out);
}

// Round 9
// 260.655 us; speedup vs baseline: 2.0748x; 1.1405x over previous
//
#include <hip/hip_runtime.h>

namespace {

typedef unsigned short ushort_t;
typedef short s16x8 __attribute__((ext_vector_type(8)));
typedef float f32x4 __attribute__((ext_vector_type(4)));

constexpr int B_ = 2, C_ = 64, H_ = 192, W_ = 192;
constexpr int C4 = 256;
constexpr int NPIX = H_ * W_;                       // 36864
constexpr size_t NT = (size_t)B_ * C4 * NPIX;       // 18,874,368
constexpr int PB = NPIX / 32;                       // 1152 pixel-blocks per batch
constexpr float EPSV = 1e-20f;

constexpr int TILE = 32;
constexpr int TLH = TILE + 2;   // 34
constexpr int LROW = 36;        // padded row: 144 B, 16B-aligned, conflict-spread
constexpr int CHUNK = 2048;     // ushorts per tensor per k-chunk (4 KB)

__device__ __forceinline__ ushort_t f2bu(float x) {
    union { float f; unsigned u; } v; v.f = x;
    unsigned r = v.u + 0x7fffu + ((v.u >> 16) & 1u);   // RNE to bf16
    return (ushort_t)(r >> 16);
}
__device__ __forceinline__ float bu2f(ushort_t h) {
    union { unsigned u; float f; } v; v.u = ((unsigned)h) << 16;
    return v.f;
}

__device__ __forceinline__ void async_ld16(const ushort_t* g, ushort_t* l) {
    __builtin_amdgcn_global_load_lds(
        (const __attribute__((address_space(1))) unsigned int*)g,
        (__attribute__((address_space(3))) unsigned int*)l, 16, 0, 0);
}

// ---------------- cw -> split bf16 hi/lo + per-block cw partial sums ----------
__global__ __launch_bounds__(256) void k_prep(const float* __restrict__ cw,
                                              ushort_t* __restrict__ cwH,
                                              ushort_t* __restrict__ cwL,
                                              float* __restrict__ partial) {
    __shared__ float red[256];
    int tid = threadIdx.x;
    int i = blockIdx.x * 256 + tid;   // grid 256 -> 65536
    float w = cw[i];
    ushort_t h = f2bu(w);
    cwH[i] = h;
    cwL[i] = f2bu(w - bu2f(h));
    red[tid] = w; __syncthreads();
    for (int s2 = 128; s2 > 0; s2 >>= 1) { if (tid < s2) red[tid] += red[tid + s2]; __syncthreads(); }
    if (tid == 0) partial[blockIdx.x] = red[0];
}

// ---------------- tiny final reduction: sw sum + cw partials ----------------
__global__ __launch_bounds__(256) void k_sums2(const float* __restrict__ sw,
                                               const float* __restrict__ partial,
                                               float* __restrict__ sums) {
    __shared__ float red[256];
    int tid = threadIdx.x;
    float a = 0.f;
    for (int i = tid; i < C4 * 9; i += 256) a += sw[i];
    red[tid] = a; __syncthreads();
    for (int s2 = 128; s2 > 0; s2 >>= 1) { if (tid < s2) red[tid] += red[tid + s2]; __syncthreads(); }
    if (tid == 0) sums[0] = red[0];
    __syncthreads();
    red[tid] = partial[tid]; __syncthreads();
    for (int s2 = 128; s2 > 0; s2 >>= 1) { if (tid < s2) red[tid] += red[tid + s2]; __syncthreads(); }
    if (tid == 0) sums[1] = red[0];
}

// ---------------- fused stage 1 + stage 2 (depthwise conv) ----------------
// R5 monolithic structure (single barrier) + strip-conv:
//  - fill u/v for ALL 4 sub-channels into 39.2 KB LDS (padded rows, 16B-aligned)
//  - one __syncthreads
//  - each thread convolves a 4-pixel strip via aligned f32x4 LDS loads
//    (48 ds_read_b128/thread instead of 288 ds_read_b32)
// Divisions cancel: U = cs_prop*s_prop = (wp*cs*s + cfd*sfd)/(wp+1),
// X = cs_spatial*s_spatial = conv(U)/sum_sw (den/(den+1e-20) == 1).
// Emits XP/YP packed split-bf16: element (b, pb, g, pix32, j) at
// ((b*PB+pb)*64 + g)*256 + pix*8 + j ; j = [hi of k=0..3 | lo of k=0..3].
__global__ __launch_bounds__(256) void k_stage12(
    const float* __restrict__ d, const float* __restrict__ cd,
    const float* __restrict__ s, const float* __restrict__ cs,
    const float* __restrict__ w_s_from_d, const float* __restrict__ w_prop,
    const float* __restrict__ sw, const float* __restrict__ sums,
    ushort_t* __restrict__ XP, ushort_t* __restrict__ YP)
{
    __shared__ float u_[4][TLH][LROW];   // 19,584 B
    __shared__ float v_[4][TLH][LROW];   // 19,584 B
    __shared__ float swl[4][9];

    int tid = threadIdx.x;
    int blk = blockIdx.x;
    constexpr int TX = W_ / TILE, TY = H_ / TILE;   // 6 x 6
    int tx0 = blk % TX; blk /= TX;
    int ty0 = blk % TY; blk /= TY;
    int c = blk % C_;
    int b = blk / C_;
    int h0 = ty0 * TILE, w0 = tx0 * TILE;

    const float* dbc  = d  + (size_t)(b * C_ + c) * NPIX;
    const float* cdbc = cd + (size_t)(b * C_ + c) * NPIX;

    if (tid < 36) swl[tid / 9][tid % 9] = sw[(c * 4 + tid / 9) * 9 + tid % 9];

    float w0s = w_s_from_d[0];
    float wp  = w_prop[c];
    float inv_wp1 = 1.f / (wp + 1.f);
    float inv_sw  = 1.f / (sums[0] + EPSV);
    float b1 = wp * inv_wp1;

    // fill: stage 1 on the halo-1 grid (34x34); only direction 0 survives the
    // reference's argmax over identical stacked copies.
    for (int i = tid; i < TLH * TLH; i += 256) {
        int y = i / TLH, x = i - y * TLH;
        int gh = h0 - 1 + y, gw = w0 - 1 + x;
        if ((unsigned)gh < (unsigned)H_ && (unsigned)gw < (unsigned)W_) {
            float mn = 0.f, cmn = 0.f, mx = 0.f, cmx = 0.f;
            if (gh >= 1 && gw >= 1) {
                size_t q = (size_t)(gh - 1) * W_ + (gw - 1);
                mn = dbc[q]; cmn = cdbc[q];
            }
            if (gh < H_ - 1 && gw < W_ - 1) {
                size_t q = (size_t)(gh + 1) * W_ + (gw + 1);
                mx = dbc[q]; cmx = cdbc[q];
            }
            float r = __fdividef(mn, mx + EPSV);
            r = fminf(fmaxf(r, 0.f), 1.f);
            float sfd = r * fmaf(w0s, r, 1.f - w0s);
            float cfd = cmn * cmx;
            float a1 = cfd * sfd * inv_wp1;
            float c1 = cfd * inv_wp1;
            size_t gbase = (size_t)((b * C_ + c) * 4) * NPIX + (size_t)gh * W_ + gw;
            #pragma unroll
            for (int k = 0; k < 4; ++k) {
                float s_v  = s[gbase + (size_t)k * NPIX];
                float cs_v = cs[gbase + (size_t)k * NPIX];
                float t = b1 * cs_v;
                u_[k][y][x] = fmaf(t, s_v, a1);   // cs_prop * s_prop
                v_[k][y][x] = t + c1;             // cs_prop
            }
        } else {
            #pragma unroll
            for (int k = 0; k < 4; ++k) { u_[k][y][x] = 0.f; v_[k][y][x] = 0.f; }
        }
    }
    __syncthreads();

    // strip-conv: thread owns output pixels (ty, txs..txs+3)
    int ty  = tid >> 3;          // 0..31
    int txs = (tid & 7) * 4;     // 0,4,...,28
    s16x8 keepX[4], keepY[4];    // per pixel: [hi k0..3 | lo k0..3]

    #pragma unroll
    for (int k = 0; k < 4; ++k) {
        f32x4 ua[3][2], va[3][2];
        #pragma unroll
        for (int dy = 0; dy < 3; ++dy) {
            ua[dy][0] = *(const f32x4*)&u_[k][ty + dy][txs];
            ua[dy][1] = *(const f32x4*)&u_[k][ty + dy][txs + 4];
            va[dy][0] = *(const f32x4*)&v_[k][ty + dy][txs];
            va[dy][1] = *(const f32x4*)&v_[k][ty + dy][txs + 4];
        }
        #pragma unroll
        for (int px = 0; px < 4; ++px) {
            float nom = 0.f, den = 0.f;
            #pragma unroll
            for (int dy = 0; dy < 3; ++dy)
                #pragma unroll
                for (int dx = 0; dx < 3; ++dx) {
                    int e = px + dx;   // 0..5, compile-time
                    float uu = (e < 4) ? ua[dy][0][e] : ua[dy][1][e - 4];
                    float vv = (e < 4) ? va[dy][0][e] : va[dy][1][e - 4];
                    float wgt = swl[k][dy * 3 + dx];
                    nom = fmaf(wgt, uu, nom);
                    den = fmaf(wgt, vv, den);
                }
            float xv = nom * inv_sw;
            float yv = den * inv_sw;
            ushort_t hx = f2bu(xv);
            ushort_t hy = f2bu(yv);
            keepX[px][k]     = (short)hx;
            keepX[px][4 + k] = (short)f2bu(xv - bu2f(hx));
            keepY[px][k]     = (short)hy;
            keepY[px][4 + k] = (short)f2bu(yv - bu2f(hy));
        }
    }

    // 64B-contiguous stores per thread (2 tensors x 4 x 16B)
    int pb = (h0 + ty) * (W_ / TILE) + (w0 >> 5);
    size_t base0 = ((size_t)(b * PB + pb) * 64 + c) * 256 + (size_t)txs * 8;
    #pragma unroll
    for (int px = 0; px < 4; ++px) {
        *(s16x8*)(XP + base0 + px * 8) = keepX[px];
        *(s16x8*)(YP + base0 + px * 8) = keepY[px];
    }
}

// ---------------- stage 3: split-bf16 MFMA GEMM, monolithic LDS stage ----------------
// 512 threads (8 waves). Block tile: 256 o x 32 pix. Wave w: o in [w*32,(w+1)*32).
// Whole B-panel (X+Y = 64 KB) staged up-front via global_load_lds; TWO compute
// barriers. Epilogue transposes via LDS for full-line 16B/lane stores.
__global__ __launch_bounds__(512, 4) void k_stage3(
    const ushort_t* __restrict__ XP, const ushort_t* __restrict__ YP,
    const ushort_t* __restrict__ cwH, const ushort_t* __restrict__ cwL,
    const float* __restrict__ sums, float* __restrict__ out)
{
    __shared__ ushort_t stg[8 * 2 * CHUNK];   // 64 KiB: 8 chunks x [X 4KB | Y 4KB]

    int tid  = threadIdx.x;
    int wave = tid >> 6, lane = tid & 63;
    int l15 = lane & 15, l4 = lane >> 4;
    int pb = blockIdx.x;
    int b  = blockIdx.y;
    int o0 = wave * 32;

    size_t xbase = (size_t)(b * PB + pb) * 16384;   // ushorts: 64 g * 256
    const ushort_t* gsrc = ((wave & 4) ? YP : XP) + xbase
                         + (size_t)(wave & 3) * 512 + (size_t)lane * 8;
    ushort_t* lbase = stg + ((wave & 4) ? CHUNK : 0) + (wave & 3) * 512;

    f32x4 accn[2][2] = {};
    f32x4 accd[2][2] = {};
    s16x8 rx[2][2], ry[2][2];
    s16x8 rAh[2][2], rAl[2][2];

#define MFMA __builtin_amdgcn_mfma_f32_16x16x32_bf16

#define STAGE(KS) async_ld16(gsrc + (size_t)(KS) * 2048, lbase + (KS) * (2 * CHUNK))

#define LOADA(AB, KS) do {                                                        \
    _Pragma("unroll")                                                             \
    for (int m = 0; m < 2; ++m) {                                                 \
        size_t ro = (size_t)(o0 + m * 16 + l15) * C4 + (KS) * 32 + l4 * 8;        \
        rAh[AB][m] = *(const s16x8*)(cwH + ro);                                   \
        rAl[AB][m] = *(const s16x8*)(cwL + ro);                                   \
    } } while (0)

#define LOADB(KS) do {                                                            \
    const ushort_t* bp = stg + (KS) * (2 * CHUNK);                                \
    _Pragma("unroll")                                                             \
    for (int n = 0; n < 2; ++n)                                                   \
        _Pragma("unroll")                                                         \
        for (int gg = 0; gg < 2; ++gg) {                                          \
            int o_ = (l4 * 2 + gg) * 256 + (n * 16 + l15) * 8;                    \
            rx[n][gg] = *(const s16x8*)(bp + o_);                                 \
            ry[n][gg] = *(const s16x8*)(bp + CHUNK + o_);                         \
        } } while (0)

#define COMPUTE(AB) do {                                                          \
    _Pragma("unroll")                                                             \
    for (int n = 0; n < 2; ++n) {                                                 \
        s16x8 bxh = __builtin_shufflevector(rx[n][0], rx[n][1], 0,1,2,3, 8,9,10,11);   \
        s16x8 bxl = __builtin_shufflevector(rx[n][0], rx[n][1], 4,5,6,7, 12,13,14,15); \
        s16x8 byh = __builtin_shufflevector(ry[n][0], ry[n][1], 0,1,2,3, 8,9,10,11);   \
        s16x8 byl = __builtin_shufflevector(ry[n][0], ry[n][1], 4,5,6,7, 12,13,14,15); \
        _Pragma("unroll")                                                         \
        for (int m = 0; m < 2; ++m) {                                             \
            accn[m][n] = MFMA(rAh[AB][m], bxh, accn[m][n], 0, 0, 0);              \
            accn[m][n] = MFMA(rAh[AB][m], bxl, accn[m][n], 0, 0, 0);              \
            accn[m][n] = MFMA(rAl[AB][m], bxh, accn[m][n], 0, 0, 0);              \
            accd[m][n] = MFMA(rAh[AB][m], byh, accd[m][n], 0, 0, 0);              \
            accd[m][n] = MFMA(rAh[AB][m], byl, accd[m][n], 0, 0, 0);              \
            accd[m][n] = MFMA(rAl[AB][m], byh, accd[m][n], 0, 0, 0);              \
        } } } while (0)

    // prologue: stage ALL 8 chunks (8 VMEM), then A0 (4 VMEM)
    STAGE(0); STAGE(1); STAGE(2); STAGE(3);
    STAGE(4); STAGE(5); STAGE(6); STAGE(7);
    __builtin_amdgcn_sched_barrier(0);
    LOADA(0, 0);
    __builtin_amdgcn_sched_barrier(0);

    // wait: own S0..S3 retired (12 issued, <=8 outstanding -> >=4 retired)
    asm volatile("s_waitcnt vmcnt(8)" ::: "memory");
    __builtin_amdgcn_s_barrier();
    __builtin_amdgcn_sched_barrier(0);

    LOADA(1, 1); LOADB(0); COMPUTE(0);
    LOADA(0, 2); LOADB(1); COMPUTE(1);
    LOADA(1, 3); LOADB(2); COMPUTE(0);
    LOADA(0, 4); LOADB(3); COMPUTE(1);

    // wait: own S0..S7 retired (28 issued by now, <=20 outstanding -> >=8 retired)
    asm volatile("s_waitcnt vmcnt(20)" ::: "memory");
    __builtin_amdgcn_s_barrier();
    __builtin_amdgcn_sched_barrier(0);

    LOADA(1, 5); LOADB(4); COMPUTE(0);
    LOADA(0, 6); LOADB(5); COMPUTE(1);
    LOADA(1, 7); LOADB(6); COMPUTE(0);
    LOADB(7); COMPUTE(1);

#undef COMPUTE
#undef LOADB
#undef LOADA
#undef STAGE
#undef MFMA

    // -------- epilogue: LDS transpose -> full-line coalesced stores --------
    float* ts = reinterpret_cast<float*>(stg);   // 256 x 36 floats = 36,864 B
    float inv_scw = 1.f / (sums[1] + EPSV);
    __syncthreads();   // all LOADB consumers of stg finished

    #pragma unroll
    for (int pass2 = 0; pass2 < 2; ++pass2) {
        #pragma unroll
        for (int m = 0; m < 2; ++m)
            #pragma unroll
            for (int n = 0; n < 2; ++n)
                #pragma unroll
                for (int r = 0; r < 4; ++r) {
                    int o = o0 + m * 16 + l4 * 4 + r;
                    float nv = accn[m][n][r], dv = accd[m][n][r];
                    float val = pass2 ? dv * inv_scw : nv / (dv + EPSV);
                    ts[o * 36 + n * 16 + l15] = val;
                }
        __syncthreads();
        size_t gb = (pass2 ? NT : 0) + (size_t)b * C4 * NPIX + (size_t)pb * 32;
        int oo = tid >> 3, j = tid & 7;
        #pragma unroll
        for (int pass = 0; pass < 4; ++pass) {
            int o = pass * 64 + oo;
            f32x4 v = *(const f32x4*)&ts[o * 36 + j * 4];
            *(f32x4*)&out[gb + (size_t)o * NPIX + j * 4] = v;
        }
        if (pass2 == 0) __syncthreads();
    }
}

} // namespace

extern "C" void kernel_launch(void* const* d_in, const int* in_sizes, int n_in,
                              void* d_out, int out_size, void* d_ws, size_t ws_size,
                              hipStream_t stream) {
    const float* d    = (const float*)d_in[0];
    const float* cd   = (const float*)d_in[1];
    const float* s    = (const float*)d_in[2];
    const float* cs   = (const float*)d_in[3];
    const float* w_s  = (const float*)d_in[4];
    const float* wprp = (const float*)d_in[5];
    const float* cw   = (const float*)d_in[6];
    const float* sw   = (const float*)d_in[7];
    float* out = (float*)d_out;

    ushort_t* XP  = (ushort_t*)d_ws;
    ushort_t* YP  = XP + 2 * NT;
    ushort_t* cwH = YP + 2 * NT;
    ushort_t* cwL = cwH + C4 * C4;
    float* sums   = (float*)(cwL + C4 * C4);
    float* partial = sums + 2;

    k_prep<<<C4, 256, 0, stream>>>(cw, cwH, cwL, partial);
    k_sums2<<<1, 256, 0, stream>>>(sw, partial, sums);
    k_stage12<<<dim3(B_ * C_ * (H_ / TILE) * (W_ / TILE)), 256, 0, stream>>>(
        d, cd, s, cs, w_s, wprp, sw, sums, XP, YP);
    k_stage3<<<dim3(PB, B_), 512, 0, stream>>>(XP, YP, cwH, cwL, sums, out);
}

// Round 11
// 235.783 us; speedup vs baseline: 2.2936x; 1.1055x over previous
//
#include <hip/hip_runtime.h>

namespace {

typedef unsigned short ushort_t;
typedef short s16x8 __attribute__((ext_vector_type(8)));
typedef float f32x4 __attribute__((ext_vector_type(4)));

constexpr int B_ = 2, C_ = 64, H_ = 192, W_ = 192;
constexpr int C4 = 256;
constexpr int NPIX = H_ * W_;                       // 36864
constexpr size_t NT = (size_t)B_ * C4 * NPIX;       // 18,874,368
constexpr int PB = NPIX / 32;                       // 1152 pixel-blocks per batch
constexpr float EPSV = 1e-20f;

constexpr int TILE = 32;
constexpr int TLH = TILE + 2;   // 34
constexpr int CHUNK = 2048;     // ushorts per tensor per k-chunk (4 KB)

__device__ __forceinline__ ushort_t f2bu(float x) {
    union { float f; unsigned u; } v; v.f = x;
    unsigned r = v.u + 0x7fffu + ((v.u >> 16) & 1u);   // RNE to bf16
    return (ushort_t)(r >> 16);
}
__device__ __forceinline__ float bu2f(ushort_t h) {
    union { unsigned u; float f; } v; v.u = ((unsigned)h) << 16;
    return v.f;
}

__device__ __forceinline__ void async_ld16(const ushort_t* g, ushort_t* l) {
    __builtin_amdgcn_global_load_lds(
        (const __attribute__((address_space(1))) unsigned int*)g,
        (__attribute__((address_space(3))) unsigned int*)l, 16, 0, 0);
}

// ---------------- cw -> split bf16 hi/lo + per-block cw partial sums ----------
__global__ __launch_bounds__(256) void k_prep(const float* __restrict__ cw,
                                              ushort_t* __restrict__ cwH,
                                              ushort_t* __restrict__ cwL,
                                              float* __restrict__ partial) {
    __shared__ float red[256];
    int tid = threadIdx.x;
    int i = blockIdx.x * 256 + tid;   // grid 256 -> 65536
    float w = cw[i];
    ushort_t h = f2bu(w);
    cwH[i] = h;
    cwL[i] = f2bu(w - bu2f(h));
    red[tid] = w; __syncthreads();
    for (int s2 = 128; s2 > 0; s2 >>= 1) { if (tid < s2) red[tid] += red[tid + s2]; __syncthreads(); }
    if (tid == 0) partial[blockIdx.x] = red[0];
}

// ---------------- tiny final reduction: sw sum + cw partials ----------------
__global__ __launch_bounds__(256) void k_sums2(const float* __restrict__ sw,
                                               const float* __restrict__ partial,
                                               float* __restrict__ sums) {
    __shared__ float red[256];
    int tid = threadIdx.x;
    float a = 0.f;
    for (int i = tid; i < C4 * 9; i += 256) a += sw[i];
    red[tid] = a; __syncthreads();
    for (int s2 = 128; s2 > 0; s2 >>= 1) { if (tid < s2) red[tid] += red[tid + s2]; __syncthreads(); }
    if (tid == 0) sums[0] = red[0];
    __syncthreads();
    red[tid] = partial[tid]; __syncthreads();
    for (int s2 = 128; s2 > 0; s2 >>= 1) { if (tid < s2) red[tid] += red[tid + s2]; __syncthreads(); }
    if (tid == 0) sums[1] = red[0];
}

// ---------------- fused stage 1 + stage 2 (depthwise conv) ----------------
// R5 monolithic structure (ONE barrier), u/v interleaved float2 in LDS
// (halves conv LDS op count: ds_read_b64 per tap). F32 precision throughout.
// Divisions cancel: U = cs_prop*s_prop = (wp*cs*s + cfd*sfd)/(wp+1),
// X = cs_spatial*s_spatial = conv(U)/sum_sw (den/(den+1e-20) == 1).
// Emits XP/YP packed split-bf16: element (b, pb, g, pix32, j) at
// ((b*PB+pb)*64 + g)*256 + pix*8 + j ; j = [hi of k=0..3 | lo of k=0..3].
__global__ __launch_bounds__(256) void k_stage12(
    const float* __restrict__ d, const float* __restrict__ cd,
    const float* __restrict__ s, const float* __restrict__ cs,
    const float* __restrict__ w_s_from_d, const float* __restrict__ w_prop,
    const float* __restrict__ sw, const float* __restrict__ sums,
    ushort_t* __restrict__ XP, ushort_t* __restrict__ YP)
{
    __shared__ float2 uv_[4][TLH][TLH + 1];   // 38,080 B (u=.x, v=.y)
    __shared__ float swl[4][9];

    int tid = threadIdx.x;
    int blk = blockIdx.x;
    constexpr int TX = W_ / TILE, TY = H_ / TILE;   // 6 x 6
    int tx0 = blk % TX; blk /= TX;
    int ty0 = blk % TY; blk /= TY;
    int c = blk % C_;
    int b = blk / C_;
    int h0 = ty0 * TILE, w0 = tx0 * TILE;

    const float* dbc  = d  + (size_t)(b * C_ + c) * NPIX;
    const float* cdbc = cd + (size_t)(b * C_ + c) * NPIX;

    if (tid < 36) swl[tid / 9][tid % 9] = sw[(c * 4 + tid / 9) * 9 + tid % 9];

    float w0s = w_s_from_d[0];
    float wp  = w_prop[c];
    float inv_wp1 = 1.f / (wp + 1.f);
    float inv_sw  = 1.f / (sums[0] + EPSV);
    float b1 = wp * inv_wp1;

    // fill: stage 1 on the halo-1 grid (34x34); only direction 0 survives the
    // reference's argmax over identical stacked copies.
    for (int i = tid; i < TLH * TLH; i += 256) {
        int y = i / TLH, x = i - y * TLH;
        int gh = h0 - 1 + y, gw = w0 - 1 + x;
        if ((unsigned)gh < (unsigned)H_ && (unsigned)gw < (unsigned)W_) {
            float mn = 0.f, cmn = 0.f, mx = 0.f, cmx = 0.f;
            if (gh >= 1 && gw >= 1) {
                size_t q = (size_t)(gh - 1) * W_ + (gw - 1);
                mn = dbc[q]; cmn = cdbc[q];
            }
            if (gh < H_ - 1 && gw < W_ - 1) {
                size_t q = (size_t)(gh + 1) * W_ + (gw + 1);
                mx = dbc[q]; cmx = cdbc[q];
            }
            float r = __fdividef(mn, mx + EPSV);
            r = fminf(fmaxf(r, 0.f), 1.f);
            float sfd = r * fmaf(w0s, r, 1.f - w0s);
            float cfd = cmn * cmx;
            float a1 = cfd * sfd * inv_wp1;
            float c1 = cfd * inv_wp1;
            size_t gbase = (size_t)((b * C_ + c) * 4) * NPIX + (size_t)gh * W_ + gw;
            #pragma unroll
            for (int k = 0; k < 4; ++k) {
                float s_v  = s[gbase + (size_t)k * NPIX];
                float cs_v = cs[gbase + (size_t)k * NPIX];
                float t = b1 * cs_v;
                uv_[k][y][x] = make_float2(fmaf(t, s_v, a1), t + c1);
            }
        } else {
            #pragma unroll
            for (int k = 0; k < 4; ++k) uv_[k][y][x] = make_float2(0.f, 0.f);
        }
    }
    __syncthreads();

    // conv: per-pixel (R5-proven pattern), one b64 read per tap
    #pragma unroll
    for (int p = 0; p < 4; ++p) {
        int i = p * 256 + tid;
        int ty = i >> 5, tx = i & 31;
        s16x8 kx, ky;
        #pragma unroll
        for (int k = 0; k < 4; ++k) {
            float nom = 0.f, den = 0.f;
            #pragma unroll
            for (int dy = 0; dy < 3; ++dy)
                #pragma unroll
                for (int dx = 0; dx < 3; ++dx) {
                    float2 P = uv_[k][ty + dy][tx + dx];
                    float wgt = swl[k][dy * 3 + dx];
                    nom = fmaf(wgt, P.x, nom);
                    den = fmaf(wgt, P.y, den);
                }
            float xv = nom * inv_sw;
            float yv = den * inv_sw;
            ushort_t hx = f2bu(xv);
            ushort_t hy = f2bu(yv);
            kx[k]     = (short)hx;
            kx[4 + k] = (short)f2bu(xv - bu2f(hx));
            ky[k]     = (short)hy;
            ky[4 + k] = (short)f2bu(yv - bu2f(hy));
        }
        int pb = (h0 + ty) * (W_ / TILE) + (w0 >> 5);
        size_t base = ((size_t)(b * PB + pb) * 64 + c) * 256 + (size_t)tx * 8;
        *(s16x8*)(XP + base) = kx;
        *(s16x8*)(YP + base) = ky;
    }
}

// ---------------- stage 3: split-bf16 MFMA GEMM, monolithic LDS stage ----------------
// 512 threads (8 waves). Block tile: 256 o x 32 pix. Wave w: o in [w*32,(w+1)*32).
// Whole B-panel (X+Y = 64 KB) staged up-front via global_load_lds; TWO compute
// barriers. Epilogue transposes via LDS for full-line 16B/lane stores.
__global__ __launch_bounds__(512, 4) void k_stage3(
    const ushort_t* __restrict__ XP, const ushort_t* __restrict__ YP,
    const ushort_t* __restrict__ cwH, const ushort_t* __restrict__ cwL,
    const float* __restrict__ sums, float* __restrict__ out)
{
    __shared__ ushort_t stg[8 * 2 * CHUNK];   // 64 KiB: 8 chunks x [X 4KB | Y 4KB]

    int tid  = threadIdx.x;
    int wave = tid >> 6, lane = tid & 63;
    int l15 = lane & 15, l4 = lane >> 4;
    int pb = blockIdx.x;
    int b  = blockIdx.y;
    int o0 = wave * 32;

    size_t xbase = (size_t)(b * PB + pb) * 16384;   // ushorts: 64 g * 256
    const ushort_t* gsrc = ((wave & 4) ? YP : XP) + xbase
                         + (size_t)(wave & 3) * 512 + (size_t)lane * 8;
    ushort_t* lbase = stg + ((wave & 4) ? CHUNK : 0) + (wave & 3) * 512;

    f32x4 accn[2][2] = {};
    f32x4 accd[2][2] = {};
    s16x8 rx[2][2], ry[2][2];
    s16x8 rAh[2][2], rAl[2][2];

#define MFMA __builtin_amdgcn_mfma_f32_16x16x32_bf16

#define STAGE(KS) async_ld16(gsrc + (size_t)(KS) * 2048, lbase + (KS) * (2 * CHUNK))

#define LOADA(AB, KS) do {                                                        \
    _Pragma("unroll")                                                             \
    for (int m = 0; m < 2; ++m) {                                                 \
        size_t ro = (size_t)(o0 + m * 16 + l15) * C4 + (KS) * 32 + l4 * 8;        \
        rAh[AB][m] = *(const s16x8*)(cwH + ro);                                   \
        rAl[AB][m] = *(const s16x8*)(cwL + ro);                                   \
    } } while (0)

#define LOADB(KS) do {                                                            \
    const ushort_t* bp = stg + (KS) * (2 * CHUNK);                                \
    _Pragma("unroll")                                                             \
    for (int n = 0; n < 2; ++n)                                                   \
        _Pragma("unroll")                                                         \
        for (int gg = 0; gg < 2; ++gg) {                                          \
            int o_ = (l4 * 2 + gg) * 256 + (n * 16 + l15) * 8;                    \
            rx[n][gg] = *(const s16x8*)(bp + o_);                                 \
            ry[n][gg] = *(const s16x8*)(bp + CHUNK + o_);                         \
        } } while (0)

#define COMPUTE(AB) do {                                                          \
    _Pragma("unroll")                                                             \
    for (int n = 0; n < 2; ++n) {                                                 \
        s16x8 bxh = __builtin_shufflevector(rx[n][0], rx[n][1], 0,1,2,3, 8,9,10,11);   \
        s16x8 bxl = __builtin_shufflevector(rx[n][0], rx[n][1], 4,5,6,7, 12,13,14,15); \
        s16x8 byh = __builtin_shufflevector(ry[n][0], ry[n][1], 0,1,2,3, 8,9,10,11);   \
        s16x8 byl = __builtin_shufflevector(ry[n][0], ry[n][1], 4,5,6,7, 12,13,14,15); \
        _Pragma("unroll")                                                         \
        for (int m = 0; m < 2; ++m) {                                             \
            accn[m][n] = MFMA(rAh[AB][m], bxh, accn[m][n], 0, 0, 0);              \
            accn[m][n] = MFMA(rAh[AB][m], bxl, accn[m][n], 0, 0, 0);              \
            accn[m][n] = MFMA(rAl[AB][m], bxh, accn[m][n], 0, 0, 0);              \
            accd[m][n] = MFMA(rAh[AB][m], byh, accd[m][n], 0, 0, 0);              \
            accd[m][n] = MFMA(rAh[AB][m], byl, accd[m][n], 0, 0, 0);              \
            accd[m][n] = MFMA(rAl[AB][m], byh, accd[m][n], 0, 0, 0);              \
        } } } while (0)

    // prologue: stage ALL 8 chunks (8 VMEM), then A0 (4 VMEM)
    STAGE(0); STAGE(1); STAGE(2); STAGE(3);
    STAGE(4); STAGE(5); STAGE(6); STAGE(7);
    __builtin_amdgcn_sched_barrier(0);
    LOADA(0, 0);
    __builtin_amdgcn_sched_barrier(0);

    // wait: own S0..S3 retired (12 issued, <=8 outstanding -> >=4 retired)
    asm volatile("s_waitcnt vmcnt(8)" ::: "memory");
    __builtin_amdgcn_s_barrier();
    __builtin_amdgcn_sched_barrier(0);

    LOADA(1, 1); LOADB(0); COMPUTE(0);
    LOADA(0, 2); LOADB(1); COMPUTE(1);
    LOADA(1, 3); LOADB(2); COMPUTE(0);
    LOADA(0, 4); LOADB(3); COMPUTE(1);

    // wait: own S0..S7 retired (28 issued by now, <=20 outstanding -> >=8 retired)
    asm volatile("s_waitcnt vmcnt(20)" ::: "memory");
    __builtin_amdgcn_s_barrier();
    __builtin_amdgcn_sched_barrier(0);

    LOADA(1, 5); LOADB(4); COMPUTE(0);
    LOADA(0, 6); LOADB(5); COMPUTE(1);
    LOADA(1, 7); LOADB(6); COMPUTE(0);
    LOADB(7); COMPUTE(1);

#undef COMPUTE
#undef LOADB
#undef LOADA
#undef STAGE
#undef MFMA

    // -------- epilogue: LDS transpose -> full-line coalesced stores --------
    float* ts = reinterpret_cast<float*>(stg);   // 256 x 36 floats = 36,864 B
    float inv_scw = 1.f / (sums[1] + EPSV);
    __syncthreads();   // all LOADB consumers of stg finished

    #pragma unroll
    for (int pass2 = 0; pass2 < 2; ++pass2) {
        #pragma unroll
        for (int m = 0; m < 2; ++m)
            #pragma unroll
            for (int n = 0; n < 2; ++n)
                #pragma unroll
                for (int r = 0; r < 4; ++r) {
                    int o = o0 + m * 16 + l4 * 4 + r;
                    float nv = accn[m][n][r], dv = accd[m][n][r];
                    float val = pass2 ? dv * inv_scw : nv / (dv + EPSV);
                    ts[o * 36 + n * 16 + l15] = val;
                }
        __syncthreads();
        size_t gb = (pass2 ? NT : 0) + (size_t)b * C4 * NPIX + (size_t)pb * 32;
        int oo = tid >> 3, j = tid & 7;
        #pragma unroll
        for (int pass = 0; pass < 4; ++pass) {
            int o = pass * 64 + oo;
            f32x4 v = *(const f32x4*)&ts[o * 36 + j * 4];
            *(f32x4*)&out[gb + (size_t)o * NPIX + j * 4] = v;
        }
        if (pass2 == 0) __syncthreads();
    }
}

} // namespace

extern "C" void kernel_launch(void* const* d_in, const int* in_sizes, int n_in,
                              void* d_out, int out_size, void* d_ws, size_t ws_size,
                              hipStream_t stream) {
    const float* d    = (const float*)d_in[0];
    const float* cd   = (const float*)d_in[1];
    const float* s    = (const float*)d_in[2];
    const float* cs   = (const float*)d_in[3];
    const float* w_s  = (const float*)d_in[4];
    const float* wprp = (const float*)d_in[5];
    const float* cw   = (const float*)d_in[6];
    const float* sw   = (const float*)d_in[7];
    float* out = (float*)d_out;

    ushort_t* XP  = (ushort_t*)d_ws;
    ushort_t* YP  = XP + 2 * NT;
    ushort_t* cwH = YP + 2 * NT;
    ushort_t* cwL = cwH + C4 * C4;
    float* sums   = (float*)(cwL + C4 * C4);
    float* partial = sums + 2;

    k_prep<<<C4, 256, 0, stream>>>(cw, cwH, cwL, partial);
    k_sums2<<<1, 256, 0, stream>>>(sw, partial, sums);
    k_stage12<<<dim3(B_ * C_ * (H_ / TILE) * (W_ / TILE)), 256, 0, stream>>>(
        d, cd, s, cs, w_s, wprp, sw, sums, XP, YP);
    k_stage3<<<dim3(PB, B_), 512, 0, stream>>>(XP, YP, cwH, cwL, sums, out);
}